// Round 11
// baseline (211.400 us; speedup 1.0000x reference)
//
#include <hip/hip_runtime.h>
#include <cstdint>
#include <cstddef>

#define DI __device__ __forceinline__

using f32x4  = __attribute__((ext_vector_type(4))) float;
using bf16x8 = __attribute__((ext_vector_type(8))) short;
using u32x2  = __attribute__((ext_vector_type(2))) unsigned int;
using u32x4  = __attribute__((ext_vector_type(4))) unsigned int;

constexpr int NT = 16384;   // tokens
constexpr int NF = 4096;    // features

// fp32 -> bf16 round-to-nearest-even
DI unsigned short f2bf(float f) {
  union { float f; unsigned u; } v; v.f = f;
  unsigned u = v.u;
  u += 0x7fffu + ((u >> 16) & 1u);
  return (unsigned short)(u >> 16);
}

// async global->LDS, 16B per lane. lds dst is wave-uniform base; HW adds lane*16.
DI void gload_lds16(const void* g, void* l) {
  __builtin_amdgcn_global_load_lds(
      (const __attribute__((address_space(1))) unsigned int*)g,
      (__attribute__((address_space(3))) unsigned int*)l, 16, 0, 0);
}

// raw barrier with LDS-only drain (keeps global loads in flight across barrier)
DI void bar_lgkm() {
  asm volatile("s_waitcnt lgkmcnt(0)" ::: "memory");
  __builtin_amdgcn_s_barrier();
  __builtin_amdgcn_sched_barrier(0);
}
// raw barrier with counted vmcnt (N newest VMEM ops may stay outstanding)
#define BAR_VM(N)                                              \
  do {                                                         \
    asm volatile("s_waitcnt vmcnt(" #N ")" ::: "memory");      \
    __builtin_amdgcn_s_barrier();                              \
    __builtin_amdgcn_sched_barrier(0);                         \
  } while (0)

// ---------------- prep: factor transpose + bf16 cast (verified r2) ----------------
// f0 [b][c][d] f32 -> f0s [d][b][c] bf16 ; f1 [a][b][c] f32 -> f1s bf16 (same layout)
__global__ void ks_prep(const float* __restrict__ f0, const float* __restrict__ f1,
                        unsigned short* __restrict__ f0s, unsigned short* __restrict__ f1s) {
  int tid = blockIdx.x * 256 + threadIdx.x;     // grid covers 2*262144
  if (tid < 262144) {
    int d = tid & 63, c = (tid >> 6) & 63, b = tid >> 12;
    f0s[d * 4096 + b * 64 + c] = f2bf(f0[tid]);
  } else {
    int t2 = tid - 262144;
    f1s[t2] = f2bf(f1[t2]);
  }
}

// ---------------- stage 1 v8: r6 structure + depth-2 x pipeline + conflict-free Ybuf
// block: 128 tokens x 8 d-planes (wave wv owns d = dg*8+wv, f0 slice persistent).
// y' layout: element = t*4096 + dg*512 + b*8 + dloc   (d-minor 16B chunks for stage2)
__global__ __launch_bounds__(512, 4) void ks1(
    const float* __restrict__ x, const unsigned short* __restrict__ f0s,
    unsigned short* __restrict__ yp)
{
  // X dbuf 2x16KB + Ybuf dbuf 2x16448 (stride 1028: 257 dwords % 32 == 1 -> 2-way max)
  __shared__ __align__(16) char L[32768 + 2 * 16448];
  char* const Xb0 = L;
  char* const Xb1 = L + 16384;
  char* const Yb0 = L + 32768;
  char* const Yb1 = L + 32768 + 16448;

  const int w  = blockIdx.x;
  const int tt = (w & 7) | ((w >> 6) << 3);   // siblings (dg 0..7) share XCD
  const int dg = (w >> 3) & 7;
  const long T0 = (long)tt * 128;

  const int tid = threadIdx.x, lane = tid & 63, wv = tid >> 6;
  const int l15 = lane & 15, lq = lane >> 4;
  const int d = dg * 8 + wv;

  bf16x8 fA[4][2];
  #pragma unroll
  for (int bt = 0; bt < 4; ++bt)
    #pragma unroll
    for (int kh = 0; kh < 2; ++kh)
      fA[bt][kh] = *(const bf16x8*)(f0s + (size_t)d * 4096 + (bt * 16 + l15) * 64 + kh * 32 + lq * 8);

  const int st_t = tid >> 5, st_c0 = (tid >> 1) & 15, st_dq = tid & 1;
  const float* const xrow0 = x + (T0 + st_t) * (long)NF + dg * 8 + st_dq * 4;
  const int wkey = (st_t & 7) << 4;

  f32x4 rA[4], rB[4];
  auto issueTo = [&](f32x4* r, int st) {
    const float* p = xrow0 + (long)st * 16 * NF + st_c0 * 4 * 64;
    r[0] = *(const f32x4*)(p);
    r[1] = *(const f32x4*)(p + 64);
    r[2] = *(const f32x4*)(p + 128);
    r[3] = *(const f32x4*)(p + 192);
  };
  auto stageXFrom = [&](const f32x4* r, char* X) {
    #pragma unroll
    for (int e = 0; e < 4; ++e) {
      int p = st_dq * 4 + e;
      unsigned lo = (unsigned)f2bf(r[0][e]) | ((unsigned)f2bf(r[1][e]) << 16);
      unsigned hi = (unsigned)f2bf(r[2][e]) | ((unsigned)f2bf(r[3][e]) << 16);
      *(u32x2*)(X + p * 2048 + st_t * 128 + ((st_c0 * 8) ^ wkey)) = u32x2{lo, hi};
    }
  };

  // prologue: depth-2 pipeline fill
  issueTo(rA, 0);
  issueTo(rB, 1);
  stageXFrom(rA, Xb0);      // waits loads(0) only
  issueTo(rA, 2);
  bar_lgkm();

  const int rkey = (l15 & 7) << 4;

  for (int st = 0; st < 8; ++st) {
    char* const Xc = (st & 1) ? Xb1 : Xb0;
    char* const Xn = (st & 1) ? Xb0 : Xb1;
    char* const Yc = (st & 1) ? Yb1 : Yb0;

    const char* Xs = Xc + wv * 2048 + l15 * 128;
    bf16x8 bx0 = *(const bf16x8*)(Xs + ((0  + lq * 16) ^ rkey));
    bf16x8 bx1 = *(const bf16x8*)(Xs + ((64 + lq * 16) ^ rkey));
    f32x4 acc[4];
    #pragma unroll
    for (int bt = 0; bt < 4; ++bt) {
      acc[bt] = __builtin_amdgcn_mfma_f32_16x16x32_bf16(fA[bt][0], bx0, (f32x4){0.f,0.f,0.f,0.f}, 0, 0, 0);
      acc[bt] = __builtin_amdgcn_mfma_f32_16x16x32_bf16(fA[bt][1], bx1, acc[bt], 0, 0, 0);
    }

    {
      char* Yw = Yc + l15 * 1028 + wv * 2;
      #pragma unroll
      for (int bt = 0; bt < 4; ++bt)
        #pragma unroll
        for (int i = 0; i < 4; ++i)
          *(unsigned short*)(Yw + (bt * 16 + lq * 4 + i) * 16) = f2bf(acc[bt][i]);
    }

    // stage tile st+1 (loads issued 2 iterations ago); refill that register set
    if (st < 7) {
      f32x4* cons = (st & 1) ? rA : rB;
      stageXFrom(cons, Xn);
      if (st < 5) issueTo(cons, st + 3);
    }

    bar_lgkm();   // LDS visibility only; prefetch loads stay in flight

    {
      const char* Yr = Yc;
      #pragma unroll
      for (int h = 0; h < 2; ++h) {
        int t = (tid >> 6) + h * 8;
        int c16 = tid & 63;
        u32x4 v = *(const u32x4*)(Yr + t * 1028 + c16 * 16);
        *(u32x4*)(yp + (T0 + st * 16 + t) * (size_t)NF + dg * 512 + c16 * 8) = v;
      }
    }
  }
}

// ---------------- stage 2 v7 (verified r10): 4-buffer, depth-3, derived vmcnt ------
// block: 512 thr = 8 waves; wave wv owns a = ag*8+wv; 128 tokens as 8 tiles of 16.
__global__ __launch_bounds__(512, 4) void ks2(
    const unsigned short* __restrict__ yp, const unsigned short* __restrict__ f1s,
    const float* __restrict__ bias, float* __restrict__ out)
{
  __shared__ __align__(16) char Yb[4][16384];   // 4 bufs x [16 t][8 dg][128 B]

  const int bid = blockIdx.x;
  const int ag  = bid & 7;
  const long T0 = (long)(bid >> 3) * 128;

  const int tid = threadIdx.x, lane = tid & 63, wv = tid >> 6;
  const int l15 = lane & 15, lq = lane >> 4;
  const int a = ag * 8 + wv;

  // persistent A operand: f1[a][b2][c2] (32 VGPR) + bias (16 VGPR)
  bf16x8 fa[4][2];
  #pragma unroll
  for (int bt = 0; bt < 4; ++bt)
    #pragma unroll
    for (int kh = 0; kh < 2; ++kh)
      fa[bt][kh] = *(const bf16x8*)(f1s + (size_t)a * 4096 + (bt * 16 + l15) * 64 + kh * 32 + lq * 8);
  f32x4 bv[4];
  #pragma unroll
  for (int bt = 0; bt < 4; ++bt)
    bv[bt] = *(const f32x4*)(bias + a * 64 + bt * 16 + lq * 4);

  auto stage = [&](int tile) {
    char* const dst = Yb[tile & 3];
    #pragma unroll
    for (int i = 0; i < 2; ++i) {
      const int trow = i * 8 + wv;
      const int g = lane ^ (trow & 7);
      const char* src = (const char*)yp + (T0 + (long)tile * 16 + trow) * 8192
                        + ((g >> 3) << 10) + ag * 128 + (g & 7) * 16;
      gload_lds16(src, dst + trow * 1024);
    }
  };

  stage(0); stage(1); stage(2);
  BAR_VM(4);                 // 6 outstanding; all-but-4 -> stage(0) resident

  #pragma unroll
  for (int j = 0; j < 8; ++j) {
    if (j + 3 < 8) stage(j + 3);      // 2 loads, consumed ~2.5 iters later

    const char* Yr = Yb[j & 3] + l15 * 1024;
    const int sw = wv ^ (l15 & 7);
    bf16x8 c0 = *(const bf16x8*)(Yr + ((lq * 8 + sw) * 16));          // dg = lq
    bf16x8 c1 = *(const bf16x8*)(Yr + (((4 + lq) * 8 + sw) * 16));    // dg = 4+lq
    f32x4 acc[4];
    #pragma unroll
    for (int bt = 0; bt < 4; ++bt) {
      acc[bt] = __builtin_amdgcn_mfma_f32_16x16x32_bf16(fa[bt][0], c0, (f32x4){0.f,0.f,0.f,0.f}, 0, 0, 0);
      acc[bt] = __builtin_amdgcn_mfma_f32_16x16x32_bf16(fa[bt][1], c1, acc[bt], 0, 0, 0);
    }
    float* op = out + (T0 + (long)j * 16 + l15) * NF + a * 64 + lq * 4;
    #pragma unroll
    for (int bt = 0; bt < 4; ++bt)
      *(f32x4*)(op + bt * 16) = acc[bt] + bv[bt];

    switch (j) {
      case 0: BAR_VM(8);  break;
      case 1: BAR_VM(12); break;
      case 2: BAR_VM(16); break;
      case 3: BAR_VM(16); break;
      case 4: BAR_VM(16); break;
      case 5: BAR_VM(14); break;
      case 6: BAR_VM(12); break;
      default: break;            // j==7: last tile
    }
  }
}

// ---------------- naive fp32 fallback (only if workspace too small) ----------------
__global__ void ks_naive(const float* __restrict__ x, const float* __restrict__ f0,
                         const float* __restrict__ f1, const float* __restrict__ bias,
                         float* __restrict__ out)
{
  __shared__ float xr[4096];
  __shared__ float yr[4096];
  long t = blockIdx.x;
  int tid = threadIdx.x;
  for (int i = tid; i < 4096; i += 256) xr[i] = x[t * 4096 + i];
  __syncthreads();
  for (int i = tid; i < 4096; i += 256) {
    int b = i >> 6, d = i & 63;
    float s = 0.f;
    for (int c = 0; c < 64; ++c) s += xr[c * 64 + d] * f0[(b * 64 + c) * 64 + d];
    yr[i] = s;
  }
  __syncthreads();
  for (int i = tid; i < 4096; i += 256) {
    int a = i >> 6;
    float s = bias[i];
    for (int c = 0; c < 64; ++c) s += yr[a * 64 + c] * f1[(size_t)i * 64 + c];
    out[t * 4096 + i] = s;
  }
}

extern "C" void kernel_launch(void* const* d_in, const int* in_sizes, int n_in,
                              void* d_out, int out_size, void* d_ws, size_t ws_size,
                              hipStream_t stream) {
  const float* x    = (const float*)d_in[0];
  const float* f0   = (const float*)d_in[1];
  const float* f1   = (const float*)d_in[2];
  const float* bias = (const float*)d_in[3];
  float* out = (float*)d_out;

  const size_t ybytes = (size_t)NT * NF * 2;          // 128 MB bf16 intermediate (y')
  const size_t fbytes = (size_t)64 * 64 * 64 * 2;     // 512 KB per factor
  if (ws_size >= ybytes + 2 * fbytes) {
    unsigned short* yw  = (unsigned short*)d_ws;
    unsigned short* f0s = yw + (size_t)NT * NF;
    unsigned short* f1s = f0s + 64 * 64 * 64;
    ks_prep<<<2048, 256, 0, stream>>>(f0, f1, f0s, f1s);
    ks1<<<1024, 512, 0, stream>>>(x, f0s, yw);
    ks2<<<1024, 512, 0, stream>>>(yw, f1s, bias, out);
  } else {
    ks_naive<<<NT, 256, 0, stream>>>(x, f0, f1, bias, out);
  }
}